// Round 2
// baseline (1651.303 us; speedup 1.0000x reference)
//
#include <hip/hip_runtime.h>
#include <cstddef>
#include <cstdint>

#define NWIN  1024
#define NTOK  64
#define CDIM  512
#define NHEAD 16
#define HDIM  32
#define MTOT  (NWIN * NTOK)   // 65536 rows
#define WSZ   (CDIM * CDIM)   // 262144 elements per weight matrix

typedef __attribute__((ext_vector_type(8))) short short8;   // 8 bf16 = 4 VGPRs
typedef __attribute__((ext_vector_type(4))) float floatx4;  // MFMA acc

// trunc-split: f = hi + lo + eps, |eps| <= 2^-16 |f|
__device__ __forceinline__ void split_bf16(float f, unsigned short& hi, unsigned short& lo) {
    unsigned u = __float_as_uint(f);
    hi = (unsigned short)(u >> 16);
    float hf = __uint_as_float(u & 0xffff0000u);
    lo = (unsigned short)(__float_as_uint(f - hf) >> 16);
}

// ---------------------------------------------------------------------------
// Split a 512x512 fp32 weight matrix into bf16 hi/lo planes (once, instead of
// per-block inside the GEMM). grid (256, nmat), block 256, 4 elems/thread.
// Three matrices per launch via blockIdx.y; dst layout: [m][hi|lo][WSZ].
// ---------------------------------------------------------------------------
__global__ __launch_bounds__(256) void splitw_kernel(
    const float* __restrict__ W0, const float* __restrict__ W1,
    const float* __restrict__ W2, unsigned short* __restrict__ dst)
{
    const int m = blockIdx.y;
    const float* W = (m == 0) ? W0 : (m == 1) ? W1 : W2;
    unsigned short* Wh = dst + (size_t)m * 2 * WSZ;
    unsigned short* Wl = Wh + WSZ;
    const int i = (blockIdx.x * 256 + threadIdx.x) * 4;
    const float4 w = *(const float4*)(W + i);
    unsigned short h0, l0, h1, l1, h2, l2, h3, l3;
    split_bf16(w.x, h0, l0); split_bf16(w.y, h1, l1);
    split_bf16(w.z, h2, l2); split_bf16(w.w, h3, l3);
    ushort4 hv = make_ushort4(h0, h1, h2, h3);
    ushort4 lv = make_ushort4(l0, l1, l2, l3);
    *(ushort4*)(Wh + i) = hv;
    *(ushort4*)(Wl + i) = lv;
}

// ---------------------------------------------------------------------------
// depthwise 3x3 + bias + ReLU -> bf16 hi/lo planes.
// grid (NWIN, 4 channel-tiles), block 256.
// ---------------------------------------------------------------------------
__global__ __launch_bounds__(256) void dwrelu_kernel(
    const float* __restrict__ x, const float* __restrict__ dww,
    const float* __restrict__ dwb,
    unsigned short* __restrict__ Rh, unsigned short* __restrict__ Rl)
{
    __shared__ float xs[64][128];
    const int b = blockIdx.x, ct = blockIdx.y;
    const int t = threadIdx.x;
    const int c0 = ct * 128;
    const float* xb = x + (size_t)b * NTOK * CDIM + c0;

    #pragma unroll
    for (int r = 0; r < 8; ++r) {               // 2048 float4s / 256 threads
        int idx = r * 256 + t;
        int n = idx >> 5, c4 = (idx & 31) * 4;
        *(float4*)&xs[n][c4] = *(const float4*)(xb + (size_t)n * CDIM + c4);
    }
    __syncthreads();

    const int cc = t & 127, g = t >> 7;
    float w[9];
    #pragma unroll
    for (int tap = 0; tap < 9; ++tap) w[tap] = dww[(size_t)(c0 + cc) * 9 + tap];
    const float bias = dwb[c0 + cc];

    for (int nn = 0; nn < 32; ++nn) {
        const int n = g * 32 + nn;
        const int i = n >> 3, j = n & 7;
        float acc = bias;
        #pragma unroll
        for (int di = 0; di < 3; ++di) {
            const int ii = i + di - 1;
            if (ii < 0 || ii >= 8) continue;
            #pragma unroll
            for (int dj = 0; dj < 3; ++dj) {
                const int jj = j + dj - 1;
                if (jj < 0 || jj >= 8) continue;
                acc = fmaf(xs[ii * 8 + jj][cc], w[di * 3 + dj], acc);
            }
        }
        acc = fmaxf(acc, 0.0f);
        unsigned short h, l;
        split_bf16(acc, h, l);
        const size_t o = ((size_t)b * NTOK + n) * CDIM + c0 + cc;
        Rh[o] = h; Rl[o] = l;
    }
}

// ---------------------------------------------------------------------------
// Split-bf16 MFMA GEMM: C[M][512] = A @ W^T + bias. A and W both given as
// hi/lo bf16 planes (W pre-split by splitw_kernel). No LDS, no barriers:
// fragments straight from global (L2/L3 resident). Block 256 = 4 waves (2x2),
// tile 128x128, 4x4 16x16x32 tiles per wave, 3 MFMAs per tile.
// ---------------------------------------------------------------------------
__global__ __launch_bounds__(256) void gemm_bb(
    const unsigned short* __restrict__ Ah, const unsigned short* __restrict__ Al,
    const unsigned short* __restrict__ Wh, const unsigned short* __restrict__ Wl,
    const float* __restrict__ bias, float* __restrict__ C)
{
    const int t = threadIdx.x;
    const int wave = t >> 6, lane = t & 63;
    const int wr = wave >> 1, wc = wave & 1;
    const int q = lane >> 4, mr = lane & 15;
    const int bm = blockIdx.x * 128, bo = blockIdx.y * 128;

    const floatx4 zero = {0.f, 0.f, 0.f, 0.f};
    floatx4 acc[4][4];
    #pragma unroll
    for (int i = 0; i < 4; ++i)
        #pragma unroll
        for (int j = 0; j < 4; ++j) acc[i][j] = zero;

    size_t aoff[4], woff[4];
    #pragma unroll
    for (int i = 0; i < 4; ++i) {
        aoff[i] = (size_t)(bm + wr * 64 + i * 16 + mr) * CDIM;
        woff[i] = (size_t)(bo + wc * 64 + i * 16 + mr) * CDIM;
    }

    for (int k0 = 0; k0 < 512; k0 += 32) {
        const int kk = k0 + q * 8;
        short8 afh[4], afl[4], wfh[4], wfl[4];
        #pragma unroll
        for (int i = 0; i < 4; ++i) {
            afh[i] = *(const short8*)(Ah + aoff[i] + kk);
            afl[i] = *(const short8*)(Al + aoff[i] + kk);
        }
        #pragma unroll
        for (int j = 0; j < 4; ++j) {
            wfh[j] = *(const short8*)(Wh + woff[j] + kk);
            wfl[j] = *(const short8*)(Wl + woff[j] + kk);
        }
        #pragma unroll
        for (int i = 0; i < 4; ++i)
            #pragma unroll
            for (int j = 0; j < 4; ++j) {
                acc[i][j] = __builtin_amdgcn_mfma_f32_16x16x32_bf16(afh[i], wfh[j], acc[i][j], 0, 0, 0);
                acc[i][j] = __builtin_amdgcn_mfma_f32_16x16x32_bf16(afh[i], wfl[j], acc[i][j], 0, 0, 0);
                acc[i][j] = __builtin_amdgcn_mfma_f32_16x16x32_bf16(afl[i], wfh[j], acc[i][j], 0, 0, 0);
            }
    }

    #pragma unroll
    for (int j = 0; j < 4; ++j) {
        const int col = bo + wc * 64 + j * 16 + mr;
        const float bv = bias[col];
        #pragma unroll
        for (int i = 0; i < 4; ++i) {
            const int row0 = bm + wr * 64 + i * 16 + q * 4;
            #pragma unroll
            for (int r = 0; r < 4; ++r)
                C[(size_t)(row0 + r) * CDIM + col] = acc[i][j][r] + bv;
        }
    }
}

// ---------------------------------------------------------------------------
// Attention per (window, head). Conflict-free LDS (Kt pad 68, Vs pad 36,
// Ss pad 65), Q in registers, parallel softmax. Output = bf16 hi/lo planes.
// grid (NWIN, NHEAD), block 256.
// ---------------------------------------------------------------------------
__global__ __launch_bounds__(256) void attn_kernel(
    const float* __restrict__ Q, const float* __restrict__ K,
    const float* __restrict__ V, const float* __restrict__ mask,
    const float* __restrict__ pos,
    unsigned short* __restrict__ AOh, unsigned short* __restrict__ AOl)
{
    __shared__ float Kt[32][68];   // transposed K: [d][token]
    __shared__ float Vs[64][36];
    __shared__ float Ss[64][65];
    const int b = blockIdx.x, h = blockIdx.y;
    const int t = threadIdx.x;
    const int n = t >> 2;              // token row (16 per wave, x4 groups)
    const int d0 = (t & 3) * 8;
    const size_t base = (size_t)b * NTOK * CDIM + h * HDIM;

    { // stage K (transposed) and V
        const float* kp = K + base + (size_t)n * CDIM + d0;
        const float4 k0v = *(const float4*)kp;
        const float4 k1v = *(const float4*)(kp + 4);
        Kt[d0 + 0][n] = k0v.x; Kt[d0 + 1][n] = k0v.y;
        Kt[d0 + 2][n] = k0v.z; Kt[d0 + 3][n] = k0v.w;
        Kt[d0 + 4][n] = k1v.x; Kt[d0 + 5][n] = k1v.y;
        Kt[d0 + 6][n] = k1v.z; Kt[d0 + 7][n] = k1v.w;
        const float* vp = V + base + (size_t)n * CDIM + d0;
        *(float4*)&Vs[n][d0]     = *(const float4*)vp;
        *(float4*)&Vs[n][d0 + 4] = *(const float4*)(vp + 4);
    }
    float qreg[32];
    {
        const float* qp = Q + base + (size_t)n * CDIM;
        #pragma unroll
        for (int c = 0; c < 8; ++c) {
            const float4 qv = *(const float4*)(qp + c * 4);
            qreg[c * 4] = qv.x; qreg[c * 4 + 1] = qv.y;
            qreg[c * 4 + 2] = qv.z; qreg[c * 4 + 3] = qv.w;
        }
    }
    __syncthreads();

    // S = scale*Q K^T + pos + mask  (thread: row n, cols j0..j0+15)
    const int j0 = (t & 3) * 16;
    float s[16];
    #pragma unroll
    for (int jj = 0; jj < 16; ++jj) s[jj] = 0.0f;
    for (int d = 0; d < 32; ++d) {
        const float qd = qreg[d];
        const float4 kt0 = *(const float4*)&Kt[d][j0];
        const float4 kt1 = *(const float4*)&Kt[d][j0 + 4];
        const float4 kt2 = *(const float4*)&Kt[d][j0 + 8];
        const float4 kt3 = *(const float4*)&Kt[d][j0 + 12];
        s[0]  = fmaf(qd, kt0.x, s[0]);  s[1]  = fmaf(qd, kt0.y, s[1]);
        s[2]  = fmaf(qd, kt0.z, s[2]);  s[3]  = fmaf(qd, kt0.w, s[3]);
        s[4]  = fmaf(qd, kt1.x, s[4]);  s[5]  = fmaf(qd, kt1.y, s[5]);
        s[6]  = fmaf(qd, kt1.z, s[6]);  s[7]  = fmaf(qd, kt1.w, s[7]);
        s[8]  = fmaf(qd, kt2.x, s[8]);  s[9]  = fmaf(qd, kt2.y, s[9]);
        s[10] = fmaf(qd, kt2.z, s[10]); s[11] = fmaf(qd, kt2.w, s[11]);
        s[12] = fmaf(qd, kt3.x, s[12]); s[13] = fmaf(qd, kt3.y, s[13]);
        s[14] = fmaf(qd, kt3.z, s[14]); s[15] = fmaf(qd, kt3.w, s[15]);
    }
    const float scale = 0.17677669529663687f;   // 32^-0.5
    const float* mrow = mask + (size_t)b * (NTOK * NTOK) + n * NTOK;
    const float* prow = pos + n * NTOK;
    #pragma unroll
    for (int jj = 0; jj < 16; ++jj)
        Ss[n][j0 + jj] = fmaf(s[jj], scale, prow[j0 + jj] + mrow[j0 + jj]);
    __syncthreads();

    // softmax: every thread computes stats for row r = t&63 (x4 redundant),
    // stashing its own 16-col group's exp values in registers (no recompute).
    const int r = t & 63, g = t >> 6;
    float mx = -1e30f;
    for (int j = 0; j < 64; ++j) mx = fmaxf(mx, Ss[r][j]);
    const int jb0 = g * 16;
    float e16[16];
    float sum = 0.0f;
    #pragma unroll
    for (int jj = 0; jj < 16; ++jj) {
        const float e = __expf(Ss[r][jb0 + jj] - mx);
        e16[jj] = e; sum += e;
    }
    #pragma unroll
    for (int gg = 1; gg < 4; ++gg) {
        const int jb = ((g + gg) & 3) * 16;
        #pragma unroll
        for (int jj = 0; jj < 16; ++jj) sum += __expf(Ss[r][jb + jj] - mx);
    }
    const float inv = 1.0f / sum;
    __syncthreads();                    // all raw-logit reads done
    #pragma unroll
    for (int jj = 0; jj < 16; ++jj)
        Ss[r][jb0 + jj] = e16[jj] * inv;
    __syncthreads();

    // O = S @ V  (thread: row n, d0..d0+7)
    float o[8];
    #pragma unroll
    for (int dd = 0; dd < 8; ++dd) o[dd] = 0.0f;
    for (int j = 0; j < 64; ++j) {
        const float sv = Ss[n][j];
        const float4 v0 = *(const float4*)&Vs[j][d0];
        const float4 v1 = *(const float4*)&Vs[j][d0 + 4];
        o[0] = fmaf(sv, v0.x, o[0]); o[1] = fmaf(sv, v0.y, o[1]);
        o[2] = fmaf(sv, v0.z, o[2]); o[3] = fmaf(sv, v0.w, o[3]);
        o[4] = fmaf(sv, v1.x, o[4]); o[5] = fmaf(sv, v1.y, o[5]);
        o[6] = fmaf(sv, v1.z, o[6]); o[7] = fmaf(sv, v1.w, o[7]);
    }
    const size_t obase = base + (size_t)n * CDIM + d0;
    #pragma unroll
    for (int dd = 0; dd < 8; ++dd) {
        unsigned short hh, ll;
        split_bf16(o[dd], hh, ll);
        AOh[obase + dd] = hh;
        AOl[obase + dd] = ll;
    }
}

// ---------------------------------------------------------------------------
extern "C" void kernel_launch(void* const* d_in, const int* in_sizes, int n_in,
                              void* d_out, int out_size, void* d_ws, size_t ws_size,
                              hipStream_t stream) {
    const float* x      = (const float*)d_in[0];
    const float* mask   = (const float*)d_in[1];
    const float* dwq_w  = (const float*)d_in[2];
    const float* dwq_b  = (const float*)d_in[3];
    const float* pwq_w  = (const float*)d_in[4];
    const float* pwq_b  = (const float*)d_in[5];
    const float* dwk_w  = (const float*)d_in[6];
    const float* dwk_b  = (const float*)d_in[7];
    const float* pwk_w  = (const float*)d_in[8];
    const float* pwk_b  = (const float*)d_in[9];
    const float* dwv_w  = (const float*)d_in[10];
    const float* dwv_b  = (const float*)d_in[11];
    const float* pwv_w  = (const float*)d_in[12];
    const float* pwv_b  = (const float*)d_in[13];
    const float* pos    = (const float*)d_in[14];
    const float* proj_w = (const float*)d_in[15];
    const float* proj_b = (const float*)d_in[16];
    float* out = (float*)d_out;

    const size_t sz = (size_t)MTOT * CDIM;      // 33,554,432 elements
    // ws layout (512 MiB, exactly full): [R: sz*4B hi/lo ushort][Q][K][V fp32]
    unsigned short* Rh = (unsigned short*)d_ws;
    unsigned short* Rl = Rh + sz;
    float* Qb = (float*)d_ws + sz;
    float* Kb = Qb + sz;
    float* Vb = Kb + sz;
    // attention output planes reuse the (dead) R region
    unsigned short* AOh = Rh;
    unsigned short* AOl = Rl;

    // W hi/lo planes: Wq/Wk/Wv live in d_out (dead scratch until the final
    // GEMM fully overwrites it); proj planes live in Qb (dead after attn).
    unsigned short* Wqkv = (unsigned short*)out;    // [3][2][WSZ]
    unsigned short* Wq_h = Wqkv;
    unsigned short* Wk_h = Wqkv + 2 * WSZ;
    unsigned short* Wv_h = Wqkv + 4 * WSZ;
    unsigned short* Wp_h = (unsigned short*)Qb;     // split after attn
    unsigned short* Wp_l = Wp_h + WSZ;

    const dim3 blk(256);
    const dim3 gdw(NWIN, 4);
    const dim3 ggm(MTOT / 128, CDIM / 128);     // (512, 4)
    const dim3 gat(NWIN, NHEAD);

    splitw_kernel<<<dim3(256, 3), blk, 0, stream>>>(pwq_w, pwk_w, pwv_w, Wqkv);
    dwrelu_kernel<<<gdw, blk, 0, stream>>>(x, dwq_w, dwq_b, Rh, Rl);
    gemm_bb<<<ggm, blk, 0, stream>>>(Rh, Rl, Wq_h, Wq_h + WSZ, pwq_b, Qb);
    dwrelu_kernel<<<gdw, blk, 0, stream>>>(x, dwk_w, dwk_b, Rh, Rl);
    gemm_bb<<<ggm, blk, 0, stream>>>(Rh, Rl, Wk_h, Wk_h + WSZ, pwk_b, Kb);
    dwrelu_kernel<<<gdw, blk, 0, stream>>>(x, dwv_w, dwv_b, Rh, Rl);
    gemm_bb<<<ggm, blk, 0, stream>>>(Rh, Rl, Wv_h, Wv_h + WSZ, pwv_b, Vb);
    attn_kernel<<<gat, blk, 0, stream>>>(Qb, Kb, Vb, mask, pos, AOh, AOl);
    splitw_kernel<<<dim3(256, 1), blk, 0, stream>>>(proj_w, proj_w, proj_w, Wp_h);
    gemm_bb<<<ggm, blk, 0, stream>>>(AOh, AOl, Wp_h, Wp_l, proj_b, out);
}

// Round 3
// 1134.888 us; speedup vs baseline: 1.4550x; 1.4550x over previous
//
#include <hip/hip_runtime.h>
#include <cstddef>
#include <cstdint>

#define NWIN  1024
#define NTOK  64
#define CDIM  512
#define NHEAD 16
#define HDIM  32
#define MTOT  (NWIN * NTOK)   // 65536 rows
#define WSZ   (CDIM * CDIM)   // 262144 elements per weight matrix

typedef __attribute__((ext_vector_type(8))) short short8;   // 8 bf16 = 4 VGPRs
typedef __attribute__((ext_vector_type(4))) float floatx4;  // MFMA acc

// trunc-split: f = hi + lo + eps, |eps| <= 2^-16 |f|
__device__ __forceinline__ void split_bf16(float f, unsigned short& hi, unsigned short& lo) {
    unsigned u = __float_as_uint(f);
    hi = (unsigned short)(u >> 16);
    float hf = __uint_as_float(u & 0xffff0000u);
    lo = (unsigned short)(__float_as_uint(f - hf) >> 16);
}

// async global->LDS, 16 B per lane. LDS dest is wave-uniform base + lane*16.
__device__ __forceinline__ void gload_lds16(const unsigned short* g, unsigned short* l) {
    __builtin_amdgcn_global_load_lds(
        (const __attribute__((address_space(1))) unsigned int*)(g),
        (__attribute__((address_space(3))) unsigned int*)(l),
        16, 0, 0);
}

// ---------------------------------------------------------------------------
// Split a 512x512 fp32 weight matrix into bf16 hi/lo planes.
// grid (256, nmat), block 256, 4 elems/thread. dst layout: [m][hi|lo][WSZ].
// ---------------------------------------------------------------------------
__global__ __launch_bounds__(256) void splitw_kernel(
    const float* __restrict__ W0, const float* __restrict__ W1,
    const float* __restrict__ W2, unsigned short* __restrict__ dst)
{
    const int m = blockIdx.y;
    const float* W = (m == 0) ? W0 : (m == 1) ? W1 : W2;
    unsigned short* Wh = dst + (size_t)m * 2 * WSZ;
    unsigned short* Wl = Wh + WSZ;
    const int i = (blockIdx.x * 256 + threadIdx.x) * 4;
    const float4 w = *(const float4*)(W + i);
    unsigned short h0, l0, h1, l1, h2, l2, h3, l3;
    split_bf16(w.x, h0, l0); split_bf16(w.y, h1, l1);
    split_bf16(w.z, h2, l2); split_bf16(w.w, h3, l3);
    ushort4 hv = make_ushort4(h0, h1, h2, h3);
    ushort4 lv = make_ushort4(l0, l1, l2, l3);
    *(ushort4*)(Wh + i) = hv;
    *(ushort4*)(Wl + i) = lv;
}

// ---------------------------------------------------------------------------
// Fused depthwise 3x3 + bias + ReLU for q,k,v in ONE pass over x.
// Reads the x tile once (LDS), applies the 3 convs, writes 3 hi/lo plane
// pairs. grid (NWIN, 4 channel-tiles), block 256.
// ---------------------------------------------------------------------------
__global__ __launch_bounds__(256) void dwrelu3_kernel(
    const float* __restrict__ x,
    const float* __restrict__ wq, const float* __restrict__ bq,
    const float* __restrict__ wk, const float* __restrict__ bk,
    const float* __restrict__ wv, const float* __restrict__ bv,
    unsigned short* __restrict__ Rqh, unsigned short* __restrict__ Rql,
    unsigned short* __restrict__ Rkh, unsigned short* __restrict__ Rkl,
    unsigned short* __restrict__ Rvh, unsigned short* __restrict__ Rvl)
{
    __shared__ float xs[64][128];
    const int b = blockIdx.x, ct = blockIdx.y;
    const int t = threadIdx.x;
    const int c0 = ct * 128;
    const float* xb = x + (size_t)b * NTOK * CDIM + c0;

    #pragma unroll
    for (int r = 0; r < 8; ++r) {               // 2048 float4s / 256 threads
        int idx = r * 256 + t;
        int n = idx >> 5, c4 = (idx & 31) * 4;
        *(float4*)&xs[n][c4] = *(const float4*)(xb + (size_t)n * CDIM + c4);
    }
    __syncthreads();

    const int cc = t & 127, g = t >> 7;
    float w0[9], w1[9], w2[9];
    #pragma unroll
    for (int tap = 0; tap < 9; ++tap) {
        w0[tap] = wq[(size_t)(c0 + cc) * 9 + tap];
        w1[tap] = wk[(size_t)(c0 + cc) * 9 + tap];
        w2[tap] = wv[(size_t)(c0 + cc) * 9 + tap];
    }
    const float b0 = bq[c0 + cc], b1 = bk[c0 + cc], b2 = bv[c0 + cc];

    for (int nn = 0; nn < 32; ++nn) {
        const int n = g * 32 + nn;
        const int i = n >> 3, j = n & 7;
        float a0 = b0, a1 = b1, a2 = b2;
        #pragma unroll
        for (int di = 0; di < 3; ++di) {
            const int ii = i + di - 1;
            if (ii < 0 || ii >= 8) continue;
            #pragma unroll
            for (int dj = 0; dj < 3; ++dj) {
                const int jj = j + dj - 1;
                if (jj < 0 || jj >= 8) continue;
                const float xv = xs[ii * 8 + jj][cc];
                a0 = fmaf(xv, w0[di * 3 + dj], a0);
                a1 = fmaf(xv, w1[di * 3 + dj], a1);
                a2 = fmaf(xv, w2[di * 3 + dj], a2);
            }
        }
        a0 = fmaxf(a0, 0.0f); a1 = fmaxf(a1, 0.0f); a2 = fmaxf(a2, 0.0f);
        unsigned short h, l;
        const size_t o = ((size_t)b * NTOK + n) * CDIM + c0 + cc;
        split_bf16(a0, h, l); Rqh[o] = h; Rql[o] = l;
        split_bf16(a1, h, l); Rkh[o] = h; Rkl[o] = l;
        split_bf16(a2, h, l); Rvh[o] = h; Rvl[o] = l;
    }
}

// ---------------------------------------------------------------------------
// Split-bf16 MFMA GEMM, m97 structure: C[M][512] = A @ W^T + bias.
// 128x128 tile, BK=32, all four bf16 planes staged to LDS via
// global_load_lds dwordx4 (32 KB), 2-barrier loop, ds_read_b128 fragments.
// LDS row = 64 B; 16B-slot XOR swizzle (slot = q ^ ((row>>1)&3)) applied on
// the READ side and inverted on the GLOBAL SOURCE address (LDS writes stay
// linear, as global_load_lds requires). Residual conflict 2-way (free).
// Block 256 = 4 waves (2x2), 4x4 16x16x32 tiles/wave, 3 MFMAs per tile.
// ---------------------------------------------------------------------------
__global__ __launch_bounds__(256) void gemm_bb(
    const unsigned short* __restrict__ Ah, const unsigned short* __restrict__ Al,
    const unsigned short* __restrict__ Wh, const unsigned short* __restrict__ Wl,
    const float* __restrict__ bias, float* __restrict__ C)
{
    __shared__ unsigned short sm[4 * 128 * 32];   // 32 KB: Ah|Al|Wh|Wl planes
    unsigned short* sAh = sm;
    unsigned short* sAl = sm + 4096;
    unsigned short* sWh = sm + 8192;
    unsigned short* sWl = sm + 12288;

    const int t = threadIdx.x;
    const int wave = t >> 6, lane = t & 63;
    const int wr = wave >> 1, wc = wave & 1;
    const int q = lane >> 4, mr = lane & 15;
    const int bm = blockIdx.x * 128, bo = blockIdx.y * 128;

    // ---- staging addresses (this wave stages rows [wave*32, wave*32+32)) ----
    const int srow = lane >> 2;          // 0..15 row within 16-row chunk
    const int sq   = lane & 3;           // 16B slot within 64B row
    const int qg   = sq ^ ((srow >> 1) & 3);   // inverse-swizzled global chunk
    const size_t arow0 = (size_t)(bm + wave * 32 + srow) * CDIM + qg * 8;
    const size_t arow1 = arow0 + (size_t)16 * CDIM;
    const size_t wrow0 = (size_t)(bo + wave * 32 + srow) * CDIM + qg * 8;
    const size_t wrow1 = wrow0 + (size_t)16 * CDIM;
    const int ldsc0 = wave * 1024;       // ushort index of chunk s=0
    const int ldsc1 = ldsc0 + 512;

    // ---- fragment read addresses (swizzled 16B slot) ----
    const int qs  = q ^ ((mr >> 1) & 3);
    const int aIx = (wr * 64 + mr) * 32 + qs * 8;   // + i*512 per tile
    const int wIx = (wc * 64 + mr) * 32 + qs * 8;

    const floatx4 zero = {0.f, 0.f, 0.f, 0.f};
    floatx4 acc[4][4];
    #pragma unroll
    for (int i = 0; i < 4; ++i)
        #pragma unroll
        for (int j = 0; j < 4; ++j) acc[i][j] = zero;

    for (int k0 = 0; k0 < 512; k0 += 32) {
        if (k0) __syncthreads();             // prev tile's reads done
        gload_lds16(Ah + arow0 + k0, sAh + ldsc0);
        gload_lds16(Ah + arow1 + k0, sAh + ldsc1);
        gload_lds16(Al + arow0 + k0, sAl + ldsc0);
        gload_lds16(Al + arow1 + k0, sAl + ldsc1);
        gload_lds16(Wh + wrow0 + k0, sWh + ldsc0);
        gload_lds16(Wh + wrow1 + k0, sWh + ldsc1);
        gload_lds16(Wl + wrow0 + k0, sWl + ldsc0);
        gload_lds16(Wl + wrow1 + k0, sWl + ldsc1);
        __syncthreads();                     // vmcnt(0) drain + barrier

        short8 afh[4], afl[4], wfh[4], wfl[4];
        #pragma unroll
        for (int i = 0; i < 4; ++i) {
            afh[i] = *(const short8*)&sAh[aIx + i * 512];
            afl[i] = *(const short8*)&sAl[aIx + i * 512];
            wfh[i] = *(const short8*)&sWh[wIx + i * 512];
            wfl[i] = *(const short8*)&sWl[wIx + i * 512];
        }
        #pragma unroll
        for (int i = 0; i < 4; ++i)
            #pragma unroll
            for (int j = 0; j < 4; ++j) {
                acc[i][j] = __builtin_amdgcn_mfma_f32_16x16x32_bf16(afh[i], wfh[j], acc[i][j], 0, 0, 0);
                acc[i][j] = __builtin_amdgcn_mfma_f32_16x16x32_bf16(afh[i], wfl[j], acc[i][j], 0, 0, 0);
                acc[i][j] = __builtin_amdgcn_mfma_f32_16x16x32_bf16(afl[i], wfh[j], acc[i][j], 0, 0, 0);
            }
    }

    #pragma unroll
    for (int j = 0; j < 4; ++j) {
        const int col = bo + wc * 64 + j * 16 + mr;
        const float bv = bias[col];
        #pragma unroll
        for (int i = 0; i < 4; ++i) {
            const int row0 = bm + wr * 64 + i * 16 + q * 4;
            #pragma unroll
            for (int r = 0; r < 4; ++r)
                C[(size_t)(row0 + r) * CDIM + col] = acc[i][j][r] + bv;
        }
    }
}

// ---------------------------------------------------------------------------
// Attention per (window, head). Conflict-free LDS (Kt pad 68, Vs pad 36,
// Ss pad 65), Q in registers, parallel softmax. Output = bf16 hi/lo planes.
// grid (NWIN, NHEAD), block 256.
// ---------------------------------------------------------------------------
__global__ __launch_bounds__(256) void attn_kernel(
    const float* __restrict__ Q, const float* __restrict__ K,
    const float* __restrict__ V, const float* __restrict__ mask,
    const float* __restrict__ pos,
    unsigned short* __restrict__ AOh, unsigned short* __restrict__ AOl)
{
    __shared__ float Kt[32][68];   // transposed K: [d][token]
    __shared__ float Vs[64][36];
    __shared__ float Ss[64][65];
    const int b = blockIdx.x, h = blockIdx.y;
    const int t = threadIdx.x;
    const int n = t >> 2;              // token row (16 per wave, x4 groups)
    const int d0 = (t & 3) * 8;
    const size_t base = (size_t)b * NTOK * CDIM + h * HDIM;

    { // stage K (transposed) and V
        const float* kp = K + base + (size_t)n * CDIM + d0;
        const float4 k0v = *(const float4*)kp;
        const float4 k1v = *(const float4*)(kp + 4);
        Kt[d0 + 0][n] = k0v.x; Kt[d0 + 1][n] = k0v.y;
        Kt[d0 + 2][n] = k0v.z; Kt[d0 + 3][n] = k0v.w;
        Kt[d0 + 4][n] = k1v.x; Kt[d0 + 5][n] = k1v.y;
        Kt[d0 + 6][n] = k1v.z; Kt[d0 + 7][n] = k1v.w;
        const float* vp = V + base + (size_t)n * CDIM + d0;
        *(float4*)&Vs[n][d0]     = *(const float4*)vp;
        *(float4*)&Vs[n][d0 + 4] = *(const float4*)(vp + 4);
    }
    float qreg[32];
    {
        const float* qp = Q + base + (size_t)n * CDIM;
        #pragma unroll
        for (int c = 0; c < 8; ++c) {
            const float4 qv = *(const float4*)(qp + c * 4);
            qreg[c * 4] = qv.x; qreg[c * 4 + 1] = qv.y;
            qreg[c * 4 + 2] = qv.z; qreg[c * 4 + 3] = qv.w;
        }
    }
    __syncthreads();

    // S = scale*Q K^T + pos + mask  (thread: row n, cols j0..j0+15)
    const int j0 = (t & 3) * 16;
    float s[16];
    #pragma unroll
    for (int jj = 0; jj < 16; ++jj) s[jj] = 0.0f;
    for (int d = 0; d < 32; ++d) {
        const float qd = qreg[d];
        const float4 kt0 = *(const float4*)&Kt[d][j0];
        const float4 kt1 = *(const float4*)&Kt[d][j0 + 4];
        const float4 kt2 = *(const float4*)&Kt[d][j0 + 8];
        const float4 kt3 = *(const float4*)&Kt[d][j0 + 12];
        s[0]  = fmaf(qd, kt0.x, s[0]);  s[1]  = fmaf(qd, kt0.y, s[1]);
        s[2]  = fmaf(qd, kt0.z, s[2]);  s[3]  = fmaf(qd, kt0.w, s[3]);
        s[4]  = fmaf(qd, kt1.x, s[4]);  s[5]  = fmaf(qd, kt1.y, s[5]);
        s[6]  = fmaf(qd, kt1.z, s[6]);  s[7]  = fmaf(qd, kt1.w, s[7]);
        s[8]  = fmaf(qd, kt2.x, s[8]);  s[9]  = fmaf(qd, kt2.y, s[9]);
        s[10] = fmaf(qd, kt2.z, s[10]); s[11] = fmaf(qd, kt2.w, s[11]);
        s[12] = fmaf(qd, kt3.x, s[12]); s[13] = fmaf(qd, kt3.y, s[13]);
        s[14] = fmaf(qd, kt3.z, s[14]); s[15] = fmaf(qd, kt3.w, s[15]);
    }
    const float scale = 0.17677669529663687f;   // 32^-0.5
    const float* mrow = mask + (size_t)b * (NTOK * NTOK) + n * NTOK;
    const float* prow = pos + n * NTOK;
    #pragma unroll
    for (int jj = 0; jj < 16; ++jj)
        Ss[n][j0 + jj] = fmaf(s[jj], scale, prow[j0 + jj] + mrow[j0 + jj]);
    __syncthreads();

    // softmax: every thread computes stats for row r = t&63 (x4 redundant),
    // stashing its own 16-col group's exp values in registers (no recompute).
    const int r = t & 63, g = t >> 6;
    float mx = -1e30f;
    for (int j = 0; j < 64; ++j) mx = fmaxf(mx, Ss[r][j]);
    const int jb0 = g * 16;
    float e16[16];
    float sum = 0.0f;
    #pragma unroll
    for (int jj = 0; jj < 16; ++jj) {
        const float e = __expf(Ss[r][jb0 + jj] - mx);
        e16[jj] = e; sum += e;
    }
    #pragma unroll
    for (int gg = 1; gg < 4; ++gg) {
        const int jb = ((g + gg) & 3) * 16;
        #pragma unroll
        for (int jj = 0; jj < 16; ++jj) sum += __expf(Ss[r][jb + jj] - mx);
    }
    const float inv = 1.0f / sum;
    __syncthreads();                    // all raw-logit reads done
    #pragma unroll
    for (int jj = 0; jj < 16; ++jj)
        Ss[r][jb0 + jj] = e16[jj] * inv;
    __syncthreads();

    // O = S @ V  (thread: row n, d0..d0+7)
    float o[8];
    #pragma unroll
    for (int dd = 0; dd < 8; ++dd) o[dd] = 0.0f;
    for (int j = 0; j < 64; ++j) {
        const float sv = Ss[n][j];
        const float4 v0 = *(const float4*)&Vs[j][d0];
        const float4 v1 = *(const float4*)&Vs[j][d0 + 4];
        o[0] = fmaf(sv, v0.x, o[0]); o[1] = fmaf(sv, v0.y, o[1]);
        o[2] = fmaf(sv, v0.z, o[2]); o[3] = fmaf(sv, v0.w, o[3]);
        o[4] = fmaf(sv, v1.x, o[4]); o[5] = fmaf(sv, v1.y, o[5]);
        o[6] = fmaf(sv, v1.z, o[6]); o[7] = fmaf(sv, v1.w, o[7]);
    }
    const size_t obase = base + (size_t)n * CDIM + d0;
    #pragma unroll
    for (int dd = 0; dd < 8; ++dd) {
        unsigned short hh, ll;
        split_bf16(o[dd], hh, ll);
        AOh[obase + dd] = hh;
        AOl[obase + dd] = ll;
    }
}

// ---------------------------------------------------------------------------
extern "C" void kernel_launch(void* const* d_in, const int* in_sizes, int n_in,
                              void* d_out, int out_size, void* d_ws, size_t ws_size,
                              hipStream_t stream) {
    const float* x      = (const float*)d_in[0];
    const float* mask   = (const float*)d_in[1];
    const float* dwq_w  = (const float*)d_in[2];
    const float* dwq_b  = (const float*)d_in[3];
    const float* pwq_w  = (const float*)d_in[4];
    const float* pwq_b  = (const float*)d_in[5];
    const float* dwk_w  = (const float*)d_in[6];
    const float* dwk_b  = (const float*)d_in[7];
    const float* pwk_w  = (const float*)d_in[8];
    const float* pwk_b  = (const float*)d_in[9];
    const float* dwv_w  = (const float*)d_in[10];
    const float* dwv_b  = (const float*)d_in[11];
    const float* pwv_w  = (const float*)d_in[12];
    const float* pwv_b  = (const float*)d_in[13];
    const float* pos    = (const float*)d_in[14];
    const float* proj_w = (const float*)d_in[15];
    const float* proj_b = (const float*)d_in[16];
    float* out = (float*)d_out;

    const size_t sz = (size_t)MTOT * CDIM;      // 33,554,432 elements
    // ws layout (512 MiB, exactly full):
    //   [0..384 MiB):  Rq(h,l) | Rk(h,l) | Rv(h,l)   (6 * 64 MiB ushort planes)
    //   [384..512):    Qb fp32
    // overlays (stream-ordered, regions dead before overwrite):
    //   Kb  <- [0,128)   after gemm-q consumed Rq
    //   Vb  <- [128,256) after gemm-k consumed Rk
    //   AO  <- [256,384) after gemm-v consumed Rv
    //   Wp  <- [384,...) after attn consumed Qb
    unsigned short* Rqh = (unsigned short*)d_ws;
    unsigned short* Rql = Rqh + sz;
    unsigned short* Rkh = Rqh + 2 * sz;
    unsigned short* Rkl = Rqh + 3 * sz;
    unsigned short* Rvh = Rqh + 4 * sz;
    unsigned short* Rvl = Rqh + 5 * sz;
    float* Qb = (float*)(Rqh + 6 * sz);
    float* Kb = (float*)d_ws;
    float* Vb = (float*)(Rqh + 2 * sz);
    unsigned short* AOh = Rvh;
    unsigned short* AOl = Rvl;

    // W hi/lo planes: Wq/Wk/Wv live in d_out (dead scratch until the final
    // GEMM fully overwrites it); proj planes live in Qb (dead after attn).
    unsigned short* Wqkv = (unsigned short*)out;    // [3][2][WSZ]
    unsigned short* Wq_h = Wqkv;
    unsigned short* Wk_h = Wqkv + 2 * WSZ;
    unsigned short* Wv_h = Wqkv + 4 * WSZ;
    unsigned short* Wp_h = (unsigned short*)Qb;     // split after attn
    unsigned short* Wp_l = Wp_h + WSZ;

    const dim3 blk(256);
    const dim3 gdw(NWIN, 4);
    const dim3 ggm(MTOT / 128, CDIM / 128);     // (512, 4)
    const dim3 gat(NWIN, NHEAD);

    splitw_kernel<<<dim3(256, 3), blk, 0, stream>>>(pwq_w, pwk_w, pwv_w, Wqkv);
    dwrelu3_kernel<<<gdw, blk, 0, stream>>>(x, dwq_w, dwq_b, dwk_w, dwk_b,
                                            dwv_w, dwv_b,
                                            Rqh, Rql, Rkh, Rkl, Rvh, Rvl);
    gemm_bb<<<ggm, blk, 0, stream>>>(Rqh, Rql, Wq_h, Wq_h + WSZ, pwq_b, Qb);
    gemm_bb<<<ggm, blk, 0, stream>>>(Rkh, Rkl, Wk_h, Wk_h + WSZ, pwk_b, Kb);
    gemm_bb<<<ggm, blk, 0, stream>>>(Rvh, Rvl, Wv_h, Wv_h + WSZ, pwv_b, Vb);
    attn_kernel<<<gat, blk, 0, stream>>>(Qb, Kb, Vb, mask, pos, AOh, AOl);
    splitw_kernel<<<dim3(256, 1), blk, 0, stream>>>(proj_w, proj_w, proj_w, Wp_h);
    gemm_bb<<<ggm, blk, 0, stream>>>(AOh, AOl, Wp_h, Wp_l, proj_b, out);
}

// Round 4
// 1110.900 us; speedup vs baseline: 1.4865x; 1.0216x over previous
//
#include <hip/hip_runtime.h>
#include <cstddef>
#include <cstdint>

#define NWIN  1024
#define NTOK  64
#define CDIM  512
#define NHEAD 16
#define HDIM  32
#define MTOT  (NWIN * NTOK)   // 65536 rows
#define WSZ   (CDIM * CDIM)   // 262144 elements per weight matrix

typedef __attribute__((ext_vector_type(8))) short short8;   // 8 bf16 = 4 VGPRs
typedef __attribute__((ext_vector_type(4))) float floatx4;  // MFMA acc

// trunc-split: f = hi + lo + eps, |eps| <= 2^-16 |f|
__device__ __forceinline__ void split_bf16(float f, unsigned short& hi, unsigned short& lo) {
    unsigned u = __float_as_uint(f);
    hi = (unsigned short)(u >> 16);
    float hf = __uint_as_float(u & 0xffff0000u);
    lo = (unsigned short)(__float_as_uint(f - hf) >> 16);
}

// async global->LDS, 16 B per lane. LDS dest is wave-uniform base + lane*16.
__device__ __forceinline__ void gload_lds16(const unsigned short* g, unsigned short* l) {
    __builtin_amdgcn_global_load_lds(
        (const __attribute__((address_space(1))) unsigned int*)(g),
        (__attribute__((address_space(3))) unsigned int*)(l),
        16, 0, 0);
}

// ---------------------------------------------------------------------------
// Split a 512x512 fp32 weight matrix into bf16 hi/lo planes.
// grid (256, nmat), block 256, 4 elems/thread. dst layout: [m][hi|lo][WSZ].
// ---------------------------------------------------------------------------
__global__ __launch_bounds__(256) void splitw_kernel(
    const float* __restrict__ W0, const float* __restrict__ W1,
    const float* __restrict__ W2, unsigned short* __restrict__ dst)
{
    const int m = blockIdx.y;
    const float* W = (m == 0) ? W0 : (m == 1) ? W1 : W2;
    unsigned short* Wh = dst + (size_t)m * 2 * WSZ;
    unsigned short* Wl = Wh + WSZ;
    const int i = (blockIdx.x * 256 + threadIdx.x) * 4;
    const float4 w = *(const float4*)(W + i);
    unsigned short h0, l0, h1, l1, h2, l2, h3, l3;
    split_bf16(w.x, h0, l0); split_bf16(w.y, h1, l1);
    split_bf16(w.z, h2, l2); split_bf16(w.w, h3, l3);
    ushort4 hv = make_ushort4(h0, h1, h2, h3);
    ushort4 lv = make_ushort4(l0, l1, l2, l3);
    *(ushort4*)(Wh + i) = hv;
    *(ushort4*)(Wl + i) = lv;
}

// ---------------------------------------------------------------------------
// Fused depthwise 3x3 + bias + ReLU for q,k,v in ONE pass over x.
// grid (NWIN, 4 channel-tiles), block 256.
// ---------------------------------------------------------------------------
__global__ __launch_bounds__(256) void dwrelu3_kernel(
    const float* __restrict__ x,
    const float* __restrict__ wq, const float* __restrict__ bq,
    const float* __restrict__ wk, const float* __restrict__ bk,
    const float* __restrict__ wv, const float* __restrict__ bv,
    unsigned short* __restrict__ Rqh, unsigned short* __restrict__ Rql,
    unsigned short* __restrict__ Rkh, unsigned short* __restrict__ Rkl,
    unsigned short* __restrict__ Rvh, unsigned short* __restrict__ Rvl)
{
    __shared__ float xs[64][128];
    const int b = blockIdx.x, ct = blockIdx.y;
    const int t = threadIdx.x;
    const int c0 = ct * 128;
    const float* xb = x + (size_t)b * NTOK * CDIM + c0;

    #pragma unroll
    for (int r = 0; r < 8; ++r) {
        int idx = r * 256 + t;
        int n = idx >> 5, c4 = (idx & 31) * 4;
        *(float4*)&xs[n][c4] = *(const float4*)(xb + (size_t)n * CDIM + c4);
    }
    __syncthreads();

    const int cc = t & 127, g = t >> 7;
    float w0[9], w1[9], w2[9];
    #pragma unroll
    for (int tap = 0; tap < 9; ++tap) {
        w0[tap] = wq[(size_t)(c0 + cc) * 9 + tap];
        w1[tap] = wk[(size_t)(c0 + cc) * 9 + tap];
        w2[tap] = wv[(size_t)(c0 + cc) * 9 + tap];
    }
    const float b0 = bq[c0 + cc], b1 = bk[c0 + cc], b2 = bv[c0 + cc];

    for (int nn = 0; nn < 32; ++nn) {
        const int n = g * 32 + nn;
        const int i = n >> 3, j = n & 7;
        float a0 = b0, a1 = b1, a2 = b2;
        #pragma unroll
        for (int di = 0; di < 3; ++di) {
            const int ii = i + di - 1;
            if (ii < 0 || ii >= 8) continue;
            #pragma unroll
            for (int dj = 0; dj < 3; ++dj) {
                const int jj = j + dj - 1;
                if (jj < 0 || jj >= 8) continue;
                const float xv = xs[ii * 8 + jj][cc];
                a0 = fmaf(xv, w0[di * 3 + dj], a0);
                a1 = fmaf(xv, w1[di * 3 + dj], a1);
                a2 = fmaf(xv, w2[di * 3 + dj], a2);
            }
        }
        a0 = fmaxf(a0, 0.0f); a1 = fmaxf(a1, 0.0f); a2 = fmaxf(a2, 0.0f);
        unsigned short h, l;
        const size_t o = ((size_t)b * NTOK + n) * CDIM + c0 + cc;
        split_bf16(a0, h, l); Rqh[o] = h; Rql[o] = l;
        split_bf16(a1, h, l); Rkh[o] = h; Rkl[o] = l;
        split_bf16(a2, h, l); Rvh[o] = h; Rvl[o] = l;
    }
}

// ---------------------------------------------------------------------------
// Split-bf16 MFMA GEMM, m97 structure: C[M][512] = A @ W^T + bias.
// 128x128 tile, BK=32, four bf16 planes staged to LDS via global_load_lds
// dwordx4 (32 KB), 2-barrier loop, swizzled ds_read_b128 fragments.
// SPLIT=true: epilogue writes bf16 hi/lo planes (for attn); else fp32.
// ---------------------------------------------------------------------------
template<bool SPLIT>
__global__ __launch_bounds__(256) void gemm_bb(
    const unsigned short* __restrict__ Ah, const unsigned short* __restrict__ Al,
    const unsigned short* __restrict__ Wh, const unsigned short* __restrict__ Wl,
    const float* __restrict__ bias, float* __restrict__ C,
    unsigned short* __restrict__ Ch, unsigned short* __restrict__ Cl)
{
    __shared__ unsigned short sm[4 * 128 * 32];   // 32 KB: Ah|Al|Wh|Wl planes
    unsigned short* sAh = sm;
    unsigned short* sAl = sm + 4096;
    unsigned short* sWh = sm + 8192;
    unsigned short* sWl = sm + 12288;

    const int t = threadIdx.x;
    const int wave = t >> 6, lane = t & 63;
    const int wr = wave >> 1, wc = wave & 1;
    const int q = lane >> 4, mr = lane & 15;
    const int bm = blockIdx.x * 128, bo = blockIdx.y * 128;

    const int srow = lane >> 2;
    const int sq   = lane & 3;
    const int qg   = sq ^ ((srow >> 1) & 3);
    const size_t arow0 = (size_t)(bm + wave * 32 + srow) * CDIM + qg * 8;
    const size_t arow1 = arow0 + (size_t)16 * CDIM;
    const size_t wrow0 = (size_t)(bo + wave * 32 + srow) * CDIM + qg * 8;
    const size_t wrow1 = wrow0 + (size_t)16 * CDIM;
    const int ldsc0 = wave * 1024;
    const int ldsc1 = ldsc0 + 512;

    const int qs  = q ^ ((mr >> 1) & 3);
    const int aIx = (wr * 64 + mr) * 32 + qs * 8;
    const int wIx = (wc * 64 + mr) * 32 + qs * 8;

    const floatx4 zero = {0.f, 0.f, 0.f, 0.f};
    floatx4 acc[4][4];
    #pragma unroll
    for (int i = 0; i < 4; ++i)
        #pragma unroll
        for (int j = 0; j < 4; ++j) acc[i][j] = zero;

    for (int k0 = 0; k0 < 512; k0 += 32) {
        if (k0) __syncthreads();
        gload_lds16(Ah + arow0 + k0, sAh + ldsc0);
        gload_lds16(Ah + arow1 + k0, sAh + ldsc1);
        gload_lds16(Al + arow0 + k0, sAl + ldsc0);
        gload_lds16(Al + arow1 + k0, sAl + ldsc1);
        gload_lds16(Wh + wrow0 + k0, sWh + ldsc0);
        gload_lds16(Wh + wrow1 + k0, sWh + ldsc1);
        gload_lds16(Wl + wrow0 + k0, sWl + ldsc0);
        gload_lds16(Wl + wrow1 + k0, sWl + ldsc1);
        __syncthreads();

        short8 afh[4], afl[4], wfh[4], wfl[4];
        #pragma unroll
        for (int i = 0; i < 4; ++i) {
            afh[i] = *(const short8*)&sAh[aIx + i * 512];
            afl[i] = *(const short8*)&sAl[aIx + i * 512];
            wfh[i] = *(const short8*)&sWh[wIx + i * 512];
            wfl[i] = *(const short8*)&sWl[wIx + i * 512];
        }
        #pragma unroll
        for (int i = 0; i < 4; ++i)
            #pragma unroll
            for (int j = 0; j < 4; ++j) {
                acc[i][j] = __builtin_amdgcn_mfma_f32_16x16x32_bf16(afh[i], wfh[j], acc[i][j], 0, 0, 0);
                acc[i][j] = __builtin_amdgcn_mfma_f32_16x16x32_bf16(afh[i], wfl[j], acc[i][j], 0, 0, 0);
                acc[i][j] = __builtin_amdgcn_mfma_f32_16x16x32_bf16(afl[i], wfh[j], acc[i][j], 0, 0, 0);
            }
    }

    #pragma unroll
    for (int j = 0; j < 4; ++j) {
        const int col = bo + wc * 64 + j * 16 + mr;
        const float bv = bias[col];
        #pragma unroll
        for (int i = 0; i < 4; ++i) {
            const int row0 = bm + wr * 64 + i * 16 + q * 4;
            #pragma unroll
            for (int r = 0; r < 4; ++r) {
                const float v = acc[i][j][r] + bv;
                const size_t off = (size_t)(row0 + r) * CDIM + col;
                if (SPLIT) {
                    unsigned short hh, ll;
                    split_bf16(v, hh, ll);
                    Ch[off] = hh; Cl[off] = ll;
                } else {
                    C[off] = v;
                }
            }
        }
    }
}

// ---------------------------------------------------------------------------
// MFMA attention per (window, head). Block 256 = 4 waves; wave w owns S rows
// [w*16, w*16+16). QK^T: K=32 (full head dim) per MFMA, 4 col-tiles x 3
// split-MFMAs, fragments straight from global bf16 planes. S -> LDS
// Ss[64][68] (fp32), wave-parallel softmax, P re-read + split, PV against
// XOR-swizzled transposed-V LDS tile (conflict-free write & b128 read).
// Output bf16 hi/lo planes. grid (NWIN, NHEAD).
// ---------------------------------------------------------------------------
__global__ __launch_bounds__(256) void attn_mfma(
    const unsigned short* __restrict__ Qh, const unsigned short* __restrict__ Ql,
    const unsigned short* __restrict__ Kh, const unsigned short* __restrict__ Kl,
    const unsigned short* __restrict__ Vh, const unsigned short* __restrict__ Vl,
    const float* __restrict__ mask, const float* __restrict__ pos,
    unsigned short* __restrict__ AOh, unsigned short* __restrict__ AOl)
{
    __shared__ unsigned short Vth[32 * 64];   // [d][tok], slot-swizzled
    __shared__ unsigned short Vtl[32 * 64];
    __shared__ float Ss[64][68];              // S / P rows (pad 68: 16B-aligned)

    const int b = blockIdx.x, h = blockIdx.y;
    const int t = threadIdx.x;
    const int w = t >> 6, lane = t & 63;
    const int mr = lane & 15, q = lane >> 4;
    const size_t base = (size_t)b * NTOK * CDIM + h * HDIM;   // ushort offset

    // ---- stage V transposed (swizzle: slot = (n>>3) ^ (d&7) ^ 2*(d>>3)) ----
    {
        const int n  = t >> 2;          // token 0..63
        const int d0 = (t & 3) * 8;     // d block
        const short8 vh8 = *(const short8*)(Vh + base + (size_t)n * CDIM + d0);
        const short8 vl8 = *(const short8*)(Vl + base + (size_t)n * CDIM + d0);
        #pragma unroll
        for (int e = 0; e < 8; ++e) {
            const int d = d0 + e;
            const int slot = (n >> 3) ^ (d & 7) ^ ((d >> 3) << 1);
            const int idx = d * 64 + slot * 8 + (n & 7);
            Vth[idx] = (unsigned short)vh8[e];
            Vtl[idx] = (unsigned short)vl8[e];
        }
    }

    // ---- Q & K fragments from global ----
    const int qrow = w * 16 + mr;
    const short8 qfh = *(const short8*)(Qh + base + (size_t)qrow * CDIM + q * 8);
    const short8 qfl = *(const short8*)(Ql + base + (size_t)qrow * CDIM + q * 8);
    short8 kfh[4], kfl[4];
    #pragma unroll
    for (int j = 0; j < 4; ++j) {
        const int krow = j * 16 + mr;
        kfh[j] = *(const short8*)(Kh + base + (size_t)krow * CDIM + q * 8);
        kfl[j] = *(const short8*)(Kl + base + (size_t)krow * CDIM + q * 8);
    }

    // ---- S strip: 4 col-tiles, 3 split-MFMAs each ----
    const floatx4 zero = {0.f, 0.f, 0.f, 0.f};
    const float scale = 0.17677669529663687f;   // 32^-0.5
    const float* mwin = mask + (size_t)b * (NTOK * NTOK);
    #pragma unroll
    for (int jt = 0; jt < 4; ++jt) {
        floatx4 a = zero;
        a = __builtin_amdgcn_mfma_f32_16x16x32_bf16(qfh, kfh[jt], a, 0, 0, 0);
        a = __builtin_amdgcn_mfma_f32_16x16x32_bf16(qfh, kfl[jt], a, 0, 0, 0);
        a = __builtin_amdgcn_mfma_f32_16x16x32_bf16(qfl, kfh[jt], a, 0, 0, 0);
        #pragma unroll
        for (int r = 0; r < 4; ++r) {
            const int row = w * 16 + q * 4 + r;     // q-token
            const int col = jt * 16 + mr;           // k-token
            const float mv = mwin[row * NTOK + col] + pos[row * NTOK + col];
            Ss[row][col] = fmaf(a[r], scale, mv);
        }
    }
    __syncthreads();      // S strips complete; Vt staged

    // ---- softmax (wave-local rows, 4 lanes/row) ----
    {
        const int sr = w * 16 + (lane >> 2);
        const int c0 = (lane & 3) * 16;
        float4 v0 = *(const float4*)&Ss[sr][c0];
        float4 v1 = *(const float4*)&Ss[sr][c0 + 4];
        float4 v2 = *(const float4*)&Ss[sr][c0 + 8];
        float4 v3 = *(const float4*)&Ss[sr][c0 + 12];
        float mx = fmaxf(fmaxf(fmaxf(v0.x, v0.y), fmaxf(v0.z, v0.w)),
                         fmaxf(fmaxf(v1.x, v1.y), fmaxf(v1.z, v1.w)));
        mx = fmaxf(mx, fmaxf(fmaxf(fmaxf(v2.x, v2.y), fmaxf(v2.z, v2.w)),
                             fmaxf(fmaxf(v3.x, v3.y), fmaxf(v3.z, v3.w))));
        mx = fmaxf(mx, __shfl_xor(mx, 1));
        mx = fmaxf(mx, __shfl_xor(mx, 2));
        v0.x = __expf(v0.x - mx); v0.y = __expf(v0.y - mx);
        v0.z = __expf(v0.z - mx); v0.w = __expf(v0.w - mx);
        v1.x = __expf(v1.x - mx); v1.y = __expf(v1.y - mx);
        v1.z = __expf(v1.z - mx); v1.w = __expf(v1.w - mx);
        v2.x = __expf(v2.x - mx); v2.y = __expf(v2.y - mx);
        v2.z = __expf(v2.z - mx); v2.w = __expf(v2.w - mx);
        v3.x = __expf(v3.x - mx); v3.y = __expf(v3.y - mx);
        v3.z = __expf(v3.z - mx); v3.w = __expf(v3.w - mx);
        float sum = (v0.x + v0.y + v0.z + v0.w) + (v1.x + v1.y + v1.z + v1.w)
                  + (v2.x + v2.y + v2.z + v2.w) + (v3.x + v3.y + v3.z + v3.w);
        sum += __shfl_xor(sum, 1);
        sum += __shfl_xor(sum, 2);
        const float inv = 1.0f / sum;
        v0.x *= inv; v0.y *= inv; v0.z *= inv; v0.w *= inv;
        v1.x *= inv; v1.y *= inv; v1.z *= inv; v1.w *= inv;
        v2.x *= inv; v2.y *= inv; v2.z *= inv; v2.w *= inv;
        v3.x *= inv; v3.y *= inv; v3.z *= inv; v3.w *= inv;
        *(float4*)&Ss[sr][c0]      = v0;
        *(float4*)&Ss[sr][c0 + 4]  = v1;
        *(float4*)&Ss[sr][c0 + 8]  = v2;
        *(float4*)&Ss[sr][c0 + 12] = v3;
    }
    __syncthreads();      // normalized P visible

    // ---- P fragments (rows w*16+mr, split to bf16 hi/lo) ----
    short8 pfh[2], pfl[2];
    #pragma unroll
    for (int ks = 0; ks < 2; ++ks) {
        const float4 p0 = *(const float4*)&Ss[w * 16 + mr][ks * 32 + q * 8];
        const float4 p1 = *(const float4*)&Ss[w * 16 + mr][ks * 32 + q * 8 + 4];
        const float pv[8] = {p0.x, p0.y, p0.z, p0.w, p1.x, p1.y, p1.z, p1.w};
        short8 hh, ll;
        #pragma unroll
        for (int e = 0; e < 8; ++e) {
            unsigned short h16, l16;
            split_bf16(pv[e], h16, l16);
            hh[e] = (short)h16; ll[e] = (short)l16;
        }
        pfh[ks] = hh; pfl[ks] = ll;
    }

    // ---- PV: O[tok][d], 2 d-tiles x 2 k-steps x 3 split-MFMAs ----
    floatx4 oa[2] = {zero, zero};
    #pragma unroll
    for (int jd = 0; jd < 2; ++jd) {
        const int d = jd * 16 + mr;
        #pragma unroll
        for (int ks = 0; ks < 2; ++ks) {
            const int c = ks * 4 + q;
            const int slot = c ^ (d & 7) ^ ((d >> 3) << 1);
            const int idx = d * 64 + slot * 8;
            const short8 vfh = *(const short8*)&Vth[idx];
            const short8 vfl = *(const short8*)&Vtl[idx];
            oa[jd] = __builtin_amdgcn_mfma_f32_16x16x32_bf16(pfh[ks], vfh, oa[jd], 0, 0, 0);
            oa[jd] = __builtin_amdgcn_mfma_f32_16x16x32_bf16(pfh[ks], vfl, oa[jd], 0, 0, 0);
            oa[jd] = __builtin_amdgcn_mfma_f32_16x16x32_bf16(pfl[ks], vfh, oa[jd], 0, 0, 0);
        }
    }

    // ---- epilogue: split O to hi/lo planes ----
    #pragma unroll
    for (int jd = 0; jd < 2; ++jd) {
        #pragma unroll
        for (int r = 0; r < 4; ++r) {
            const int row = w * 16 + q * 4 + r;
            const size_t off = base + (size_t)row * CDIM + jd * 16 + mr;
            unsigned short hh, ll;
            split_bf16(oa[jd][r], hh, ll);
            AOh[off] = hh; AOl[off] = ll;
        }
    }
}

// ---------------------------------------------------------------------------
extern "C" void kernel_launch(void* const* d_in, const int* in_sizes, int n_in,
                              void* d_out, int out_size, void* d_ws, size_t ws_size,
                              hipStream_t stream) {
    const float* x      = (const float*)d_in[0];
    const float* mask   = (const float*)d_in[1];
    const float* dwq_w  = (const float*)d_in[2];
    const float* dwq_b  = (const float*)d_in[3];
    const float* pwq_w  = (const float*)d_in[4];
    const float* pwq_b  = (const float*)d_in[5];
    const float* dwk_w  = (const float*)d_in[6];
    const float* dwk_b  = (const float*)d_in[7];
    const float* pwk_w  = (const float*)d_in[8];
    const float* pwk_b  = (const float*)d_in[9];
    const float* dwv_w  = (const float*)d_in[10];
    const float* dwv_b  = (const float*)d_in[11];
    const float* pwv_w  = (const float*)d_in[12];
    const float* pwv_b  = (const float*)d_in[13];
    const float* pos    = (const float*)d_in[14];
    const float* proj_w = (const float*)d_in[15];
    const float* proj_b = (const float*)d_in[16];
    float* out = (float*)d_out;

    const size_t sz = (size_t)MTOT * CDIM;      // 33,554,432 elements
    // ws layout (512 MiB = 8 ushort planes of 64 MiB):
    //   planes 0-5: Rq(h,l) Rk(h,l) Rv(h,l)
    //   planes 6-7: Qh Ql            <- gemm-q (reads planes 0-1)
    //   Kh Kl -> planes 0-1          <- gemm-k (reads 2-3; Rq dead)
    //   Vh Vl -> planes 2-3          <- gemm-v (reads 4-5; Rk dead)
    //   AO    -> planes 4-5          <- attn  (reads 6-7,0-1,2-3; Rv dead)
    //   Wp    -> plane 6 start       <- splitw (Q dead after attn)
    unsigned short* P0 = (unsigned short*)d_ws;
    unsigned short* Rqh = P0;          unsigned short* Rql = P0 + sz;
    unsigned short* Rkh = P0 + 2*sz;   unsigned short* Rkl = P0 + 3*sz;
    unsigned short* Rvh = P0 + 4*sz;   unsigned short* Rvl = P0 + 5*sz;
    unsigned short* Qh  = P0 + 6*sz;   unsigned short* Ql  = P0 + 7*sz;
    unsigned short* KhP = P0;          unsigned short* KlP = P0 + sz;
    unsigned short* VhP = P0 + 2*sz;   unsigned short* VlP = P0 + 3*sz;
    unsigned short* AOh = P0 + 4*sz;   unsigned short* AOl = P0 + 5*sz;
    unsigned short* Wp_h = P0 + 6*sz;  unsigned short* Wp_l = Wp_h + WSZ;

    // Wq/Wk/Wv hi/lo planes live in d_out (dead until final GEMM overwrites)
    unsigned short* Wqkv = (unsigned short*)out;    // [3][2][WSZ]
    unsigned short* Wq_h = Wqkv;
    unsigned short* Wk_h = Wqkv + 2 * WSZ;
    unsigned short* Wv_h = Wqkv + 4 * WSZ;

    const dim3 blk(256);
    const dim3 gdw(NWIN, 4);
    const dim3 ggm(MTOT / 128, CDIM / 128);     // (512, 4)
    const dim3 gat(NWIN, NHEAD);

    splitw_kernel<<<dim3(256, 3), blk, 0, stream>>>(pwq_w, pwk_w, pwv_w, Wqkv);
    dwrelu3_kernel<<<gdw, blk, 0, stream>>>(x, dwq_w, dwq_b, dwk_w, dwk_b,
                                            dwv_w, dwv_b,
                                            Rqh, Rql, Rkh, Rkl, Rvh, Rvl);
    gemm_bb<true><<<ggm, blk, 0, stream>>>(Rqh, Rql, Wq_h, Wq_h + WSZ, pwq_b,
                                           nullptr, Qh, Ql);
    gemm_bb<true><<<ggm, blk, 0, stream>>>(Rkh, Rkl, Wk_h, Wk_h + WSZ, pwk_b,
                                           nullptr, KhP, KlP);
    gemm_bb<true><<<ggm, blk, 0, stream>>>(Rvh, Rvl, Wv_h, Wv_h + WSZ, pwv_b,
                                           nullptr, VhP, VlP);
    attn_mfma<<<gat, blk, 0, stream>>>(Qh, Ql, KhP, KlP, VhP, VlP,
                                       mask, pos, AOh, AOl);
    splitw_kernel<<<dim3(256, 1), blk, 0, stream>>>(proj_w, proj_w, proj_w, Wp_h);
    gemm_bb<false><<<ggm, blk, 0, stream>>>(AOh, AOl, Wp_h, Wp_l, proj_b,
                                            out, nullptr, nullptr);
}